// Round 7
// baseline (458.594 us; speedup 1.0000x reference)
//
#include <hip/hip_runtime.h>
#include <hip/hip_bf16.h>

typedef __attribute__((ext_vector_type(8))) short bf16x8;
typedef __attribute__((ext_vector_type(4))) float f32x4;

static __device__ __forceinline__ unsigned short f2bf(float f) {
    unsigned u = __builtin_bit_cast(unsigned, f);
    unsigned rounding = 0x7fffu + ((u >> 16) & 1u);
    u += rounding;
    return (unsigned short)(u >> 16);
}

static __device__ __forceinline__ void async_copy16(const void* g, void* l) {
    __builtin_amdgcn_global_load_lds(
        (const __attribute__((address_space(1))) unsigned int*)g,
        (__attribute__((address_space(3))) unsigned int*)l,
        16, 0, 0);
}

#define BARRIER() __builtin_amdgcn_s_barrier()
#define VM0()    do { asm volatile("s_waitcnt vmcnt(0)" ::: "memory"); \
                      __builtin_amdgcn_sched_barrier(0); } while (0)

// fast erf-gelu via tanh approximation (|err| <= ~3e-3, threshold margin 0.07+)
static __device__ __forceinline__ float fast_gelu(float y) {
    float u = 0.7978845608028654f * y * (1.0f + 0.044715f * y * y);
    float au = fminf(fabsf(u), 9.0f);
    float e = __expf(-2.0f * au);
    float th = (1.0f - e) * __builtin_amdgcn_rcpf(1.0f + e);
    th = (u < 0.0f) ? -th : th;
    return 0.5f * y * (1.0f + th);
}

// ---------------- LayerNorm (fp32) -> bf16 cast ----------------
__global__ __launch_bounds__(256) void ln_cast_kernel(
    const float* __restrict__ x, const float* __restrict__ gamma,
    const float* __restrict__ beta, unsigned short* __restrict__ out) {
    const int row = blockIdx.x;
    const int t = threadIdx.x;
    const float4 v = ((const float4*)(x + (size_t)row * 1024))[t];

    float s  = v.x + v.y + v.z + v.w;
    float ss = v.x * v.x + v.y * v.y + v.z * v.z + v.w * v.w;
    #pragma unroll
    for (int off = 32; off; off >>= 1) {
        s  += __shfl_down(s, off);
        ss += __shfl_down(ss, off);
    }
    __shared__ float red[8];
    const int wid = t >> 6, lane = t & 63;
    if (lane == 0) { red[wid] = s; red[wid + 4] = ss; }
    __syncthreads();
    if (t == 0) {
        float S  = red[0] + red[1] + red[2] + red[3];
        float SS = red[4] + red[5] + red[6] + red[7];
        float mu = S * (1.0f / 1024.0f);
        float var = SS * (1.0f / 1024.0f) - mu * mu;
        red[0] = mu;
        red[1] = rsqrtf(var + 1e-7f);
    }
    __syncthreads();
    const float mu = red[0], rs = red[1];
    const float4 g = ((const float4*)gamma)[t];
    const float4 b = ((const float4*)beta)[t];

    ushort4 pk;
    pk.x = f2bf((v.x - mu) * rs * g.x + b.x);
    pk.y = f2bf((v.y - mu) * rs * g.y + b.y);
    pk.z = f2bf((v.z - mu) * rs * g.z + b.z);
    pk.w = f2bf((v.w - mu) * rs * g.w + b.w);
    ((ushort4*)(out + (size_t)row * 1024))[t] = pk;
}

// ---------------- W [1024][4096] fp32 -> Wt [4096][1024] bf16 ----------------
__global__ __launch_bounds__(256) void wt_cast_kernel(
    const float* __restrict__ W, unsigned short* __restrict__ Wt) {
    __shared__ float tile[32][33];
    const int bx = blockIdx.x;
    const int by = blockIdx.y;
    const int tx = threadIdx.x & 31;
    const int ty = threadIdx.x >> 5;
    #pragma unroll
    for (int i = 0; i < 4; ++i) {
        int k = by * 32 + ty + i * 8;
        tile[ty + i * 8][tx] = W[(size_t)k * 4096 + bx * 32 + tx];
    }
    __syncthreads();
    #pragma unroll
    for (int i = 0; i < 4; ++i) {
        int n = bx * 32 + ty + i * 8;
        Wt[(size_t)n * 1024 + by * 32 + tx] = f2bf(tile[tx][ty + i * 8]);
    }
}

// ---------------- GEMM 128x128, BK=64: A via dbuf LDS, B direct global->reg ----
// LDS only 32KB (A only) -> 3 blocks/CU. B frags double-buffered in registers,
// prefetched one K-tile ahead (L2-resident Wt, 8MB). ds_read traffic halved.
__global__ __launch_bounds__(256, 3) void gemm_kernel(
    const unsigned short* __restrict__ A, const unsigned short* __restrict__ Wt,
    const float* __restrict__ bias, float* __restrict__ out) {
    __shared__ char lds_mem[32768];   // [2 bufs][A 16KB]

    const int bid = blockIdx.x;                 // 4096 blocks, %8==0 -> bijective
    const int swz = (bid & 7) * 512 + (bid >> 3);
    const int bm = swz >> 5;                    // 0..127
    const int bn = swz & 31;                    // 0..31

    const int t = threadIdx.x;
    const int lane = t & 63;
    const int wid = t >> 6;
    const int wm = wid >> 1, wn = wid & 1;
    const int lrow = lane & 15;
    const int lk = lane >> 4;                   // 0..3

    // A staging: thread t -> row (t>>3)+32*i, 16B chunk (t&7); src pre-swizzled
    const int srr = t >> 3;                     // 0..31
    const int sch = t & 7;
    const int sgc = sch ^ (srr & 7);
    const unsigned short* gA = A + (size_t)(bm * 128 + srr) * 1024 + sgc * 8;
    const int lst = srr * 128 + sch * 16;

    auto stage = [&](int kt, char* buf) {
        #pragma unroll
        for (int i = 0; i < 4; ++i)
            async_copy16(gA + (size_t)(i * 32) * 1024 + kt * 64, buf + i * 32 * 128 + lst);
    };

    // B: per-lane direct global reads. frag row = bn*128 + wn*64 + ni*16 + lrow,
    // chunk lk (ck0) and 4+lk (ck1) -> 16 lanes x 64B contiguous segments.
    const unsigned short* gBw = Wt + (size_t)(bn * 128 + wn * 64 + lrow) * 1024 + lk * 8;
    auto loadB = [&](int kt, bf16x8 (*b)[2]) {
        #pragma unroll
        for (int ni = 0; ni < 4; ++ni) {
            const unsigned short* p = gBw + (size_t)(ni * 16) * 1024 + kt * 64;
            b[ni][0] = *(const bf16x8*)(p);
            b[ni][1] = *(const bf16x8*)(p + 32);
        }
    };

    // A read-side swizzle: chunk c of frag-row r -> slot (c ^ (r&7)); r&7 == lrow&7
    const int ck0 = ((lk) ^ (lrow & 7)) * 16;
    const int ck1 = ((4 + lk) ^ (lrow & 7)) * 16;
    const int aBase = (wm * 64 + lrow) * 128;           // + mi*16*128

    f32x4 acc[4][4];
    #pragma unroll
    for (int i = 0; i < 4; ++i)
        #pragma unroll
        for (int j = 0; j < 4; ++j) acc[i][j] = (f32x4)0.0f;

    float bv[4];
    #pragma unroll
    for (int ni = 0; ni < 4; ++ni) bv[ni] = bias[bn * 128 + wn * 64 + ni * 16 + lrow];

    bf16x8 bf0[4][2], bf1[4][2];

    // prologue: B kt=0 -> bf0, A kt=0 -> buf0
    loadB(0, bf0);
    stage(0, lds_mem);
    VM0();
    BARRIER();

    auto body = [&](int kt, char* cbuf, char* nbuf, bf16x8 (*bcur)[2],
                    bf16x8 (*bnext)[2], bool notLast) {
        bf16x8 af[4][2];
        #pragma unroll
        for (int mi = 0; mi < 4; ++mi) {
            const char* p = cbuf + aBase + mi * 16 * 128;
            af[mi][0] = *(const bf16x8*)(p + ck0);
            af[mi][1] = *(const bf16x8*)(p + ck1);
        }
        if (notLast) {
            loadB(kt + 1, bnext);     // B kt+1 -> regs (L2 hit, drains at VM0)
            stage(kt + 1, nbuf);      // A kt+1 -> other LDS buf
        }
        __builtin_amdgcn_s_setprio(1);
        #pragma unroll
        for (int mi = 0; mi < 4; ++mi)
            #pragma unroll
            for (int ni = 0; ni < 4; ++ni) {
                acc[mi][ni] = __builtin_amdgcn_mfma_f32_16x16x32_bf16(af[mi][0], bcur[ni][0], acc[mi][ni], 0, 0, 0);
                acc[mi][ni] = __builtin_amdgcn_mfma_f32_16x16x32_bf16(af[mi][1], bcur[ni][1], acc[mi][ni], 0, 0, 0);
            }
        __builtin_amdgcn_s_setprio(0);
        if (notLast) {
            VM0();       // A-stage landed + bnext regs valid
            BARRIER();   // all waves done reading cbuf
        }
    };

    char* lds0 = lds_mem;
    char* lds1 = lds_mem + 16384;
    for (int kt2 = 0; kt2 < 7; ++kt2) {
        body(2 * kt2,     lds0, lds1, bf0, bf1, true);
        body(2 * kt2 + 1, lds1, lds0, bf1, bf0, true);
    }
    body(14, lds0, lds1, bf0, bf1, true);
    body(15, lds1, lds0, bf1, bf0, false);

    // ---- epilogue: bias + fast gelu, fp32 store
    #pragma unroll
    for (int mi = 0; mi < 4; ++mi) {
        const int row0 = bm * 128 + wm * 64 + mi * 16 + lk * 4;
        #pragma unroll
        for (int ni = 0; ni < 4; ++ni) {
            const int col = bn * 128 + wn * 64 + ni * 16 + lrow;
            #pragma unroll
            for (int r = 0; r < 4; ++r) {
                float y = acc[mi][ni][r] + bv[ni];
                out[(size_t)(row0 + r) * 4096 + col] = fast_gelu(y);
            }
        }
    }
}

extern "C" void kernel_launch(void* const* d_in, const int* in_sizes, int n_in,
                              void* d_out, int out_size, void* d_ws, size_t ws_size,
                              hipStream_t stream) {
    const float* hidden = (const float*)d_in[0];
    const float* gamma  = (const float*)d_in[1];
    const float* beta   = (const float*)d_in[2];
    const float* W      = (const float*)d_in[3];
    const float* bias   = (const float*)d_in[4];
    float* out = (float*)d_out;

    unsigned short* Abf = (unsigned short*)d_ws;
    unsigned short* Wt  = (unsigned short*)((char*)d_ws + (size_t)16384 * 1024 * 2);

    ln_cast_kernel<<<16384, 256, 0, stream>>>(hidden, gamma, beta, Abf);
    wt_cast_kernel<<<dim3(128, 32), 256, 0, stream>>>(W, Wt);
    gemm_kernel<<<4096, 256, 0, stream>>>(Abf, Wt, bias, out);
}

// Round 8
// 335.951 us; speedup vs baseline: 1.3651x; 1.3651x over previous
//
#include <hip/hip_runtime.h>
#include <hip/hip_bf16.h>

typedef __attribute__((ext_vector_type(8))) short bf16x8;
typedef __attribute__((ext_vector_type(4))) float f32x4;

static __device__ __forceinline__ unsigned short f2bf(float f) {
    unsigned u = __builtin_bit_cast(unsigned, f);
    unsigned rounding = 0x7fffu + ((u >> 16) & 1u);
    u += rounding;
    return (unsigned short)(u >> 16);
}

static __device__ __forceinline__ void async_copy16(const void* g, void* l) {
    __builtin_amdgcn_global_load_lds(
        (const __attribute__((address_space(1))) unsigned int*)g,
        (__attribute__((address_space(3))) unsigned int*)l,
        16, 0, 0);
}

#define BARRIER() __builtin_amdgcn_s_barrier()
#define VM0()    do { asm volatile("s_waitcnt vmcnt(0)" ::: "memory"); \
                      __builtin_amdgcn_sched_barrier(0); } while (0)

// fast erf-gelu via tanh approximation (|err| <= ~3e-3, threshold margin 0.07+)
static __device__ __forceinline__ float fast_gelu(float y) {
    float u = 0.7978845608028654f * y * (1.0f + 0.044715f * y * y);
    float au = fminf(fabsf(u), 9.0f);
    float e = __expf(-2.0f * au);
    float th = (1.0f - e) * __builtin_amdgcn_rcpf(1.0f + e);
    th = (u < 0.0f) ? -th : th;
    return 0.5f * y * (1.0f + th);
}

// ---------------- LayerNorm (fp32) -> bf16 cast ----------------
__global__ __launch_bounds__(256) void ln_cast_kernel(
    const float* __restrict__ x, const float* __restrict__ gamma,
    const float* __restrict__ beta, unsigned short* __restrict__ out) {
    const int row = blockIdx.x;
    const int t = threadIdx.x;
    const float4 v = ((const float4*)(x + (size_t)row * 1024))[t];

    float s  = v.x + v.y + v.z + v.w;
    float ss = v.x * v.x + v.y * v.y + v.z * v.z + v.w * v.w;
    #pragma unroll
    for (int off = 32; off; off >>= 1) {
        s  += __shfl_down(s, off);
        ss += __shfl_down(ss, off);
    }
    __shared__ float red[8];
    const int wid = t >> 6, lane = t & 63;
    if (lane == 0) { red[wid] = s; red[wid + 4] = ss; }
    __syncthreads();
    if (t == 0) {
        float S  = red[0] + red[1] + red[2] + red[3];
        float SS = red[4] + red[5] + red[6] + red[7];
        float mu = S * (1.0f / 1024.0f);
        float var = SS * (1.0f / 1024.0f) - mu * mu;
        red[0] = mu;
        red[1] = rsqrtf(var + 1e-7f);
    }
    __syncthreads();
    const float mu = red[0], rs = red[1];
    const float4 g = ((const float4*)gamma)[t];
    const float4 b = ((const float4*)beta)[t];

    ushort4 pk;
    pk.x = f2bf((v.x - mu) * rs * g.x + b.x);
    pk.y = f2bf((v.y - mu) * rs * g.y + b.y);
    pk.z = f2bf((v.z - mu) * rs * g.z + b.z);
    pk.w = f2bf((v.w - mu) * rs * g.w + b.w);
    ((ushort4*)(out + (size_t)row * 1024))[t] = pk;
}

// ---------------- W [1024][4096] fp32 -> Wt [4096][1024] bf16 ----------------
__global__ __launch_bounds__(256) void wt_cast_kernel(
    const float* __restrict__ W, unsigned short* __restrict__ Wt) {
    __shared__ float tile[32][33];
    const int bx = blockIdx.x;
    const int by = blockIdx.y;
    const int tx = threadIdx.x & 31;
    const int ty = threadIdx.x >> 5;
    #pragma unroll
    for (int i = 0; i < 4; ++i) {
        int k = by * 32 + ty + i * 8;
        tile[ty + i * 8][tx] = W[(size_t)k * 4096 + bx * 32 + tx];
    }
    __syncthreads();
    #pragma unroll
    for (int i = 0; i < 4; ++i) {
        int n = bx * 32 + ty + i * 8;
        Wt[(size_t)n * 1024 + by * 32 + tx] = f2bf(tile[tx][ty + i * 8]);
    }
}

// ---------------- GEMM 128x128, BK=64: A via dbuf LDS, B direct global->reg ----
// B double-buffered in REGISTERS via macro-expanded named arrays (all constant
// indices -> VGPRs, no scratch). LDS = 32KB (A only). ds_read volume halved.
__global__ __launch_bounds__(256, 2) void gemm_kernel(
    const unsigned short* __restrict__ A, const unsigned short* __restrict__ Wt,
    const float* __restrict__ bias, float* __restrict__ out) {
    __shared__ char lds_mem[32768];   // [2 bufs][A 16KB]

    const int bid = blockIdx.x;                 // 4096 blocks, %8==0 -> bijective
    const int swz = (bid & 7) * 512 + (bid >> 3);
    const int bm = swz >> 5;                    // 0..127
    const int bn = swz & 31;                    // 0..31

    const int t = threadIdx.x;
    const int lane = t & 63;
    const int wid = t >> 6;
    const int wm = wid >> 1, wn = wid & 1;
    const int lrow = lane & 15;
    const int lk = lane >> 4;                   // 0..3

    // A staging: thread t -> row (t>>3)+32*i, 16B chunk (t&7); src pre-swizzled
    const int srr = t >> 3;                     // 0..31
    const int sch = t & 7;
    const int sgc = sch ^ (srr & 7);
    const unsigned short* gA = A + (size_t)(bm * 128 + srr) * 1024 + sgc * 8;
    const int lst = srr * 128 + sch * 16;

    auto stage = [&](int kt, char* buf) {
        #pragma unroll
        for (int i = 0; i < 4; ++i)
            async_copy16(gA + (size_t)(i * 32) * 1024 + kt * 64, buf + i * 32 * 128 + lst);
    };

    // B: per-lane direct global reads; frag row = bn*128 + wn*64 + ni*16 + lrow.
    const unsigned short* gBw = Wt + (size_t)(bn * 128 + wn * 64 + lrow) * 1024 + lk * 8;

    // A read-side swizzle: chunk c of frag-row r -> slot (c ^ (r&7)); r&7 == lrow&7
    const int ck0 = ((lk) ^ (lrow & 7)) * 16;
    const int ck1 = ((4 + lk) ^ (lrow & 7)) * 16;
    const int aBase = (wm * 64 + lrow) * 128;           // + mi*16*128

    f32x4 acc[4][4];
    #pragma unroll
    for (int i = 0; i < 4; ++i)
        #pragma unroll
        for (int j = 0; j < 4; ++j) acc[i][j] = (f32x4)0.0f;

    float bv[4];
    #pragma unroll
    for (int ni = 0; ni < 4; ++ni) bv[ni] = bias[bn * 128 + wn * 64 + ni * 16 + lrow];

    bf16x8 b0[4][2], b1[4][2];   // named buffers; ALL accesses literal-indexed

#define LOADB(B, KT) do {                                                       \
    B[0][0] = *(const bf16x8*)(gBw + (size_t)(0 * 16) * 1024 + (KT) * 64);      \
    B[0][1] = *(const bf16x8*)(gBw + (size_t)(0 * 16) * 1024 + (KT) * 64 + 32); \
    B[1][0] = *(const bf16x8*)(gBw + (size_t)(1 * 16) * 1024 + (KT) * 64);      \
    B[1][1] = *(const bf16x8*)(gBw + (size_t)(1 * 16) * 1024 + (KT) * 64 + 32); \
    B[2][0] = *(const bf16x8*)(gBw + (size_t)(2 * 16) * 1024 + (KT) * 64);      \
    B[2][1] = *(const bf16x8*)(gBw + (size_t)(2 * 16) * 1024 + (KT) * 64 + 32); \
    B[3][0] = *(const bf16x8*)(gBw + (size_t)(3 * 16) * 1024 + (KT) * 64);      \
    B[3][1] = *(const bf16x8*)(gBw + (size_t)(3 * 16) * 1024 + (KT) * 64 + 32); \
} while (0)

#define KBODY(KT, CBUF, NBUF, BCUR, BNXT, NOTLAST) do {                         \
    bf16x8 af[4][2];                                                            \
    _Pragma("unroll")                                                           \
    for (int mi = 0; mi < 4; ++mi) {                                            \
        const char* p = (CBUF) + aBase + mi * 16 * 128;                         \
        af[mi][0] = *(const bf16x8*)(p + ck0);                                  \
        af[mi][1] = *(const bf16x8*)(p + ck1);                                  \
    }                                                                           \
    if (NOTLAST) {                                                              \
        LOADB(BNXT, (KT) + 1);                                                  \
        stage((KT) + 1, (NBUF));                                                \
    }                                                                           \
    __builtin_amdgcn_s_setprio(1);                                              \
    _Pragma("unroll")                                                           \
    for (int mi = 0; mi < 4; ++mi)                                              \
        _Pragma("unroll")                                                       \
        for (int ni = 0; ni < 4; ++ni) {                                        \
            acc[mi][ni] = __builtin_amdgcn_mfma_f32_16x16x32_bf16(              \
                af[mi][0], BCUR[ni][0], acc[mi][ni], 0, 0, 0);                  \
            acc[mi][ni] = __builtin_amdgcn_mfma_f32_16x16x32_bf16(              \
                af[mi][1], BCUR[ni][1], acc[mi][ni], 0, 0, 0);                  \
        }                                                                       \
    __builtin_amdgcn_s_setprio(0);                                              \
    if (NOTLAST) { VM0(); BARRIER(); }                                          \
} while (0)

    char* lds0 = lds_mem;
    char* lds1 = lds_mem + 16384;

    // prologue: B kt=0 -> b0, A kt=0 -> lds0
    LOADB(b0, 0);
    stage(0, lds0);
    VM0();
    BARRIER();

    #pragma unroll 1
    for (int kt2 = 0; kt2 < 7; ++kt2) {
        KBODY(2 * kt2,     lds0, lds1, b0, b1, true);
        KBODY(2 * kt2 + 1, lds1, lds0, b1, b0, true);
    }
    KBODY(14, lds0, lds1, b0, b1, true);
    KBODY(15, lds1, lds0, b1, b0, false);

#undef KBODY
#undef LOADB

    // ---- epilogue: bias + fast gelu, fp32 store
    #pragma unroll
    for (int mi = 0; mi < 4; ++mi) {
        const int row0 = bm * 128 + wm * 64 + mi * 16 + lk * 4;
        #pragma unroll
        for (int ni = 0; ni < 4; ++ni) {
            const int col = bn * 128 + wn * 64 + ni * 16 + lrow;
            #pragma unroll
            for (int r = 0; r < 4; ++r) {
                float y = acc[mi][ni][r] + bv[ni];
                out[(size_t)(row0 + r) * 4096 + col] = fast_gelu(y);
            }
        }
    }
}

extern "C" void kernel_launch(void* const* d_in, const int* in_sizes, int n_in,
                              void* d_out, int out_size, void* d_ws, size_t ws_size,
                              hipStream_t stream) {
    const float* hidden = (const float*)d_in[0];
    const float* gamma  = (const float*)d_in[1];
    const float* beta   = (const float*)d_in[2];
    const float* W      = (const float*)d_in[3];
    const float* bias   = (const float*)d_in[4];
    float* out = (float*)d_out;

    unsigned short* Abf = (unsigned short*)d_ws;
    unsigned short* Wt  = (unsigned short*)((char*)d_ws + (size_t)16384 * 1024 * 2);

    ln_cast_kernel<<<16384, 256, 0, stream>>>(hidden, gamma, beta, Abf);
    wt_cast_kernel<<<dim3(128, 32), 256, 0, stream>>>(W, Wt);
    gemm_kernel<<<4096, 256, 0, stream>>>(Abf, Wt, bias, out);
}

// Round 9
// 184.625 us; speedup vs baseline: 2.4839x; 1.8196x over previous
//
#include <hip/hip_runtime.h>
#include <hip/hip_bf16.h>

typedef __attribute__((ext_vector_type(8))) short bf16x8;
typedef __attribute__((ext_vector_type(4))) float f32x4;

static __device__ __forceinline__ unsigned short f2bf(float f) {
    unsigned u = __builtin_bit_cast(unsigned, f);
    unsigned rounding = 0x7fffu + ((u >> 16) & 1u);
    u += rounding;
    return (unsigned short)(u >> 16);
}

static __device__ __forceinline__ void async_copy16(const void* g, void* l) {
    __builtin_amdgcn_global_load_lds(
        (const __attribute__((address_space(1))) unsigned int*)g,
        (__attribute__((address_space(3))) unsigned int*)l,
        16, 0, 0);
}

#define BARRIER() __builtin_amdgcn_s_barrier()
#define VM0()    do { asm volatile("s_waitcnt vmcnt(0)" ::: "memory"); \
                      __builtin_amdgcn_sched_barrier(0); } while (0)

// fast erf-gelu via tanh approximation (|err| <= ~3e-3, threshold margin 0.07+)
static __device__ __forceinline__ float fast_gelu(float y) {
    float u = 0.7978845608028654f * y * (1.0f + 0.044715f * y * y);
    float au = fminf(fabsf(u), 9.0f);
    float e = __expf(-2.0f * au);
    float th = (1.0f - e) * __builtin_amdgcn_rcpf(1.0f + e);
    th = (u < 0.0f) ? -th : th;
    return 0.5f * y * (1.0f + th);
}

// ---------------- LayerNorm (fp32) -> bf16 cast ----------------
__global__ __launch_bounds__(256) void ln_cast_kernel(
    const float* __restrict__ x, const float* __restrict__ gamma,
    const float* __restrict__ beta, unsigned short* __restrict__ out) {
    const int row = blockIdx.x;
    const int t = threadIdx.x;
    const float4 v = ((const float4*)(x + (size_t)row * 1024))[t];

    float s  = v.x + v.y + v.z + v.w;
    float ss = v.x * v.x + v.y * v.y + v.z * v.z + v.w * v.w;
    #pragma unroll
    for (int off = 32; off; off >>= 1) {
        s  += __shfl_down(s, off);
        ss += __shfl_down(ss, off);
    }
    __shared__ float red[8];
    const int wid = t >> 6, lane = t & 63;
    if (lane == 0) { red[wid] = s; red[wid + 4] = ss; }
    __syncthreads();
    if (t == 0) {
        float S  = red[0] + red[1] + red[2] + red[3];
        float SS = red[4] + red[5] + red[6] + red[7];
        float mu = S * (1.0f / 1024.0f);
        float var = SS * (1.0f / 1024.0f) - mu * mu;
        red[0] = mu;
        red[1] = rsqrtf(var + 1e-7f);
    }
    __syncthreads();
    const float mu = red[0], rs = red[1];
    const float4 g = ((const float4*)gamma)[t];
    const float4 b = ((const float4*)beta)[t];

    ushort4 pk;
    pk.x = f2bf((v.x - mu) * rs * g.x + b.x);
    pk.y = f2bf((v.y - mu) * rs * g.y + b.y);
    pk.z = f2bf((v.z - mu) * rs * g.z + b.z);
    pk.w = f2bf((v.w - mu) * rs * g.w + b.w);
    ((ushort4*)(out + (size_t)row * 1024))[t] = pk;
}

// ---------------- W [1024][4096] fp32 -> Wt [4096][1024] bf16 ----------------
__global__ __launch_bounds__(256) void wt_cast_kernel(
    const float* __restrict__ W, unsigned short* __restrict__ Wt) {
    __shared__ float tile[32][33];
    const int bx = blockIdx.x;
    const int by = blockIdx.y;
    const int tx = threadIdx.x & 31;
    const int ty = threadIdx.x >> 5;
    #pragma unroll
    for (int i = 0; i < 4; ++i) {
        int k = by * 32 + ty + i * 8;
        tile[ty + i * 8][tx] = W[(size_t)k * 4096 + bx * 32 + tx];
    }
    __syncthreads();
    #pragma unroll
    for (int i = 0; i < 4; ++i) {
        int n = bx * 32 + ty + i * 8;
        Wt[(size_t)n * 1024 + by * 32 + tx] = f2bf(tile[tx][ty + i * 8]);
    }
}

// ---------------- GEMM 256x256 tile, BK=64, dbuf LDS 128KB, 8 waves (2Mx4N) ----
// R6 2-phase schedule at m201 geometry: better LDS economy
// (ds_read/output -25%, lds_write/output -50% vs 128^2).
// Wave tile 128x64. Proven conflict-free 16-row read pattern + (r&7) XOR swizzle.
__global__ __launch_bounds__(512, 2) void gemm_kernel(
    const unsigned short* __restrict__ A, const unsigned short* __restrict__ Wt,
    const float* __restrict__ bias, float* __restrict__ out) {
    __shared__ char lds_mem[131072];   // [2 bufs][A 32KB | B 32KB]

    const int bid = blockIdx.x;                 // 1024 blocks, %8==0 -> bijective
    const int swz = (bid & 7) * 128 + (bid >> 3);
    const int bm = swz >> 4;                    // 0..63
    const int bn = swz & 15;                    // 0..15

    const int t = threadIdx.x;
    const int lane = t & 63;
    const int wid = t >> 6;                     // 0..7
    const int wm = wid >> 2;                    // 0..1  (M half)
    const int wn = wid & 3;                     // 0..3  (N quarter)
    const int lrow = lane & 15;
    const int lk = lane >> 4;                   // 0..3

    // staging: thread t -> row (t>>3)+64*i, 16B chunk (t&7); src pre-swizzled
    const int srr = t >> 3;                     // 0..63
    const int sch = t & 7;
    const int sgc = sch ^ (srr & 7);
    const unsigned short* gA = A  + (size_t)(bm * 256 + srr) * 1024 + sgc * 8;
    const unsigned short* gB = Wt + (size_t)(bn * 256 + srr) * 1024 + sgc * 8;
    const int lst = srr * 128 + sch * 16;

    auto stage = [&](int kt, char* buf) {
        #pragma unroll
        for (int i = 0; i < 4; ++i) {
            async_copy16(gA + (size_t)(i * 64) * 1024 + kt * 64, buf + i * 64 * 128 + lst);
            async_copy16(gB + (size_t)(i * 64) * 1024 + kt * 64, buf + 32768 + i * 64 * 128 + lst);
        }
    };

    // read-side swizzle: chunk c of frag-row r -> slot (c ^ (r&7)); r&7 == lrow&7
    const int ck0 = ((lk) ^ (lrow & 7)) * 16;
    const int ck1 = ((4 + lk) ^ (lrow & 7)) * 16;
    const int aBase = (wm * 128 + lrow) * 128;           // + mi*16*128, mi 0..7
    const int bBase = 32768 + (wn * 64 + lrow) * 128;    // + ni*16*128, ni 0..3

    f32x4 acc[8][4];
    #pragma unroll
    for (int i = 0; i < 8; ++i)
        #pragma unroll
        for (int j = 0; j < 4; ++j) acc[i][j] = (f32x4)0.0f;

    float bv[4];
    #pragma unroll
    for (int ni = 0; ni < 4; ++ni) bv[ni] = bias[bn * 256 + wn * 64 + ni * 16 + lrow];

    // prologue
    stage(0, lds_mem);
    VM0();
    BARRIER();

    const int NKT = 16;
    for (int kt = 0; kt < NKT; ++kt) {
        char* cbuf = lds_mem + ((kt & 1) << 16);
        char* nbuf = lds_mem + (((kt + 1) & 1) << 16);

        // B frags first (live across the whole mi loop: 8 reads -> 32 VGPR)
        bf16x8 bf[4][2];
        #pragma unroll
        for (int ni = 0; ni < 4; ++ni) {
            const char* p = cbuf + bBase + ni * 16 * 128;
            bf[ni][0] = *(const bf16x8*)(p + ck0);
            bf[ni][1] = *(const bf16x8*)(p + ck1);
        }

        if (kt + 1 < NKT) stage(kt + 1, nbuf);   // issue next-tile loads

        // per-mi: 2 A reads + 8 MFMA (compiler pipelines lgkmcnt)
        __builtin_amdgcn_s_setprio(1);
        #pragma unroll
        for (int mi = 0; mi < 8; ++mi) {
            const char* p = cbuf + aBase + mi * 16 * 128;
            bf16x8 a0 = *(const bf16x8*)(p + ck0);
            bf16x8 a1 = *(const bf16x8*)(p + ck1);
            #pragma unroll
            for (int ni = 0; ni < 4; ++ni) {
                acc[mi][ni] = __builtin_amdgcn_mfma_f32_16x16x32_bf16(a0, bf[ni][0], acc[mi][ni], 0, 0, 0);
                acc[mi][ni] = __builtin_amdgcn_mfma_f32_16x16x32_bf16(a1, bf[ni][1], acc[mi][ni], 0, 0, 0);
            }
        }
        __builtin_amdgcn_s_setprio(0);

        if (kt + 1 < NKT) {
            VM0();       // next-tile gload_lds landed (hidden under reads+MFMA)
            BARRIER();   // all waves done with cbuf -> safe to restage next iter
        }
    }

    // ---- epilogue: bias + fast gelu, fp32 store
    #pragma unroll
    for (int mi = 0; mi < 8; ++mi) {
        const int row0 = bm * 256 + wm * 128 + mi * 16 + lk * 4;
        #pragma unroll
        for (int ni = 0; ni < 4; ++ni) {
            const int col = bn * 256 + wn * 64 + ni * 16 + lrow;
            #pragma unroll
            for (int r = 0; r < 4; ++r) {
                float y = acc[mi][ni][r] + bv[ni];
                out[(size_t)(row0 + r) * 4096 + col] = fast_gelu(y);
            }
        }
    }
}

extern "C" void kernel_launch(void* const* d_in, const int* in_sizes, int n_in,
                              void* d_out, int out_size, void* d_ws, size_t ws_size,
                              hipStream_t stream) {
    const float* hidden = (const float*)d_in[0];
    const float* gamma  = (const float*)d_in[1];
    const float* beta   = (const float*)d_in[2];
    const float* W      = (const float*)d_in[3];
    const float* bias   = (const float*)d_in[4];
    float* out = (float*)d_out;

    unsigned short* Abf = (unsigned short*)d_ws;
    unsigned short* Wt  = (unsigned short*)((char*)d_ws + (size_t)16384 * 1024 * 2);

    ln_cast_kernel<<<16384, 256, 0, stream>>>(hidden, gamma, beta, Abf);
    wt_cast_kernel<<<dim3(128, 32), 256, 0, stream>>>(W, Wt);
    gemm_kernel<<<1024, 512, 0, stream>>>(Abf, Wt, bias, out);
}